// Round 8
// baseline (124.374 us; speedup 1.0000x reference)
//
#include <hip/hip_runtime.h>
#include <hip/hip_bf16.h>

typedef __bf16 bf16;
typedef bf16 bf16x4 __attribute__((ext_vector_type(4)));
typedef bf16 bf16x8 __attribute__((ext_vector_type(8)));
typedef float f32x4 __attribute__((ext_vector_type(4)));

#define GLOAD16(g, l) __builtin_amdgcn_global_load_lds( \
    (const __attribute__((address_space(1))) void*)(g),  \
    (__attribute__((address_space(3))) void*)(l), 16, 0, 0)

#define EXP2F(x) __builtin_amdgcn_exp2f(x)
#define MFMA16(a, b, c) __builtin_amdgcn_mfma_f32_16x16x32_bf16(a, b, c, 0, 0, 0)

// ---------------- prep: cast x + transpose-cast both weights ----------------
// grid 6144: [0,2048) cast x (8 elems/thr); [2048,5120) Wqkv^T; [5120,6144) Wout^T
__global__ __launch_bounds__(256) void prep(const float* __restrict__ x,
                                            const float* __restrict__ Wqkv,
                                            const float* __restrict__ Wout,
                                            bf16* __restrict__ xb,
                                            bf16* __restrict__ wqkvT,
                                            bf16* __restrict__ woutT) {
  int id = blockIdx.x, tid = threadIdx.x;
  if (id < 2048) {
    int i = id * 256 + tid;
    const float4* p = (const float4*)x + (size_t)i * 2;
    float4 a = p[0], b = p[1];
    bf16x8 o;
    o[0] = (bf16)a.x; o[1] = (bf16)a.y; o[2] = (bf16)a.z; o[3] = (bf16)a.w;
    o[4] = (bf16)b.x; o[5] = (bf16)b.y; o[6] = (bf16)b.z; o[7] = (bf16)b.w;
    ((bf16x8*)xb)[i] = o;
  } else {
    __shared__ float tile[32][33];
    const float* src; bf16* dst; int N, j;
    if (id < 5120) { src = Wqkv; dst = wqkvT; N = 3072; j = id - 2048; }
    else           { src = Wout; dst = woutT; N = 1024; j = id - 5120; }
    int ntile = N / 32;
    int n0 = (j % ntile) * 32, k0 = (j / ntile) * 32;
    int tx = tid & 31, ty = tid >> 5;   // 32 x 8
#pragma unroll
    for (int i = 0; i < 4; i++)
      tile[ty + 8 * i][tx] = src[(size_t)(k0 + ty + 8 * i) * N + n0 + tx];
    __syncthreads();
#pragma unroll
    for (int i = 0; i < 4; i++)
      dst[(size_t)(n0 + ty + 8 * i) * 1024 + k0 + tx] = (bf16)tile[tx][ty + 8 * i];
  }
}

// ---- GEMM mainloop: BK=32, double-buffered (stage t+1 BEFORE compute t) ----
// 4 waves (2x2), wave tile 64x64. LDS rows 64 B, chunk-XOR swizzle
// (ch ^= row&3): inverse on global source (rule #21), same XOR on frag reads.
__device__ __forceinline__ void gemm_mainloop_db(const bf16* __restrict__ A,
                                                 const bf16* __restrict__ Bt,
                                                 int K, int m0, int n0,
                                                 f32x4 acc[4][4],
                                                 bf16* As, bf16* Bs) {
  int tid = threadIdx.x;
  int lane = tid & 63;
  int wave = tid >> 6;
  int wr = wave >> 1, wc = wave & 1;
  int c16 = lane & 15, g = lane >> 4;
  f32x4 z = {0.f, 0.f, 0.f, 0.f};
#pragma unroll
  for (int m = 0; m < 4; m++)
#pragma unroll
    for (int n = 0; n < 4; n++) acc[m][n] = z;

  auto stage = [&](int kt, int b) {
#pragma unroll
    for (int i = 0; i < 2; i++) {
      int cc = tid + i * 256;           // 0..511 chunks of 16B (A tile 8KB)
      int r = cc >> 2, ch = cc & 3;
      int sc = ch ^ (r & 3);
      GLOAD16(A + (size_t)(m0 + r) * K + kt * 32 + sc * 8, As + b * 4096 + cc * 8);
    }
#pragma unroll
    for (int i = 0; i < 2; i++) {
      int cc = tid + i * 256;
      int r = cc >> 2, ch = cc & 3;
      int sc = ch ^ (r & 3);
      GLOAD16(Bt + (size_t)(n0 + r) * K + kt * 32 + sc * 8, Bs + b * 4096 + cc * 8);
    }
  };

  // hoisted swizzled frag byte-offsets
  int aoff[4], boff[4];
#pragma unroll
  for (int m = 0; m < 4; m++) {
    int ar = wr * 64 + m * 16 + c16;
    aoff[m] = ar * 64 + ((g ^ (ar & 3)) << 4);
  }
#pragma unroll
  for (int n = 0; n < 4; n++) {
    int br = wc * 64 + n * 16 + c16;
    boff[n] = br * 64 + ((g ^ (br & 3)) << 4);
  }

  int nk = K >> 5;
  stage(0, 0);
  __syncthreads();                       // drains stage(0)
  for (int kt = 0; kt < nk; ++kt) {
    int cb = kt & 1;
    if (kt + 1 < nk) stage(kt + 1, cb ^ 1);   // prefetch under compute
    const char* Ab = (const char*)(As + cb * 4096);
    const char* Bb = (const char*)(Bs + cb * 4096);
    bf16x8 af[4], bfr[4];
#pragma unroll
    for (int m = 0; m < 4; m++) af[m] = *(const bf16x8*)(Ab + aoff[m]);
#pragma unroll
    for (int n = 0; n < 4; n++) bfr[n] = *(const bf16x8*)(Bb + boff[n]);
    __builtin_amdgcn_s_setprio(1);
#pragma unroll
    for (int m = 0; m < 4; m++)
#pragma unroll
      for (int n = 0; n < 4; n++)
        acc[m][n] = MFMA16(af[m], bfr[n], acc[m][n]);
    __builtin_amdgcn_s_setprio(0);
    if (kt + 1 < nk) __syncthreads();    // drains prefetch + buffer-swap barrier
  }
}

// ---- QKV GEMM: x[4096,1024] @ WqkvT[3072,1024]^T -> q,k scaled / vT ----
__global__ __launch_bounds__(256) void gemm_qkv(const bf16* __restrict__ A,
                                                const bf16* __restrict__ Bt,
                                                bf16* __restrict__ q,
                                                bf16* __restrict__ kk,
                                                bf16* __restrict__ vt) {
  __shared__ bf16 As[2][128 * 32];   // 16 KB
  __shared__ bf16 Bs[2][128 * 32];   // 16 KB
  int id = blockIdx.x;
  int xc = id & 7, k = id >> 3;            // k in [0,96)
  int bn = xc * 3 + (k % 3), bm = k / 3;   // bijective; 3 bn-cols per XCD
  int m0 = bm * 128, n0 = bn * 128;
  f32x4 acc[4][4];
  gemm_mainloop_db(A, Bt, 1024, m0, n0, acc, As[0], Bs[0]);
  int lane = threadIdx.x & 63;
  int wave = threadIdx.x >> 6;
  int wr = wave >> 1, wc = wave & 1;
  int c16 = lane & 15, g = lane >> 4;
  int which = n0 >> 10;
  const float QSCALE = 0.125f * 1.4426950408889634f;
  if (which == 2) {
#pragma unroll
    for (int m = 0; m < 4; m++)
#pragma unroll
      for (int n = 0; n < 4; n++) {
        int gm0 = m0 + wr * 64 + m * 16 + g * 4;
        int gn = n0 + wc * 64 + n * 16 + c16;
        int rem = gn & 1023, h = rem >> 6, d = rem & 63;
        int b = gm0 >> 11, t0 = gm0 & 2047;
        size_t bh = (size_t)(b * 16 + h);
        bf16x4 pv;
        pv[0] = (bf16)acc[m][n][0]; pv[1] = (bf16)acc[m][n][1];
        pv[2] = (bf16)acc[m][n][2]; pv[3] = (bf16)acc[m][n][3];
        *(bf16x4*)(vt + (bh * 64 + d) * 2048 + t0) = pv;
      }
  } else {
#pragma unroll
    for (int m = 0; m < 4; m++)
#pragma unroll
      for (int n = 0; n < 4; n++)
#pragma unroll
        for (int j = 0; j < 4; j++) {
          int gm = m0 + wr * 64 + m * 16 + g * 4 + j;
          int gn = n0 + wc * 64 + n * 16 + c16;
          int rem = gn & 1023, h = rem >> 6, d = rem & 63;
          int b = gm >> 11, t = gm & 2047;
          float v = acc[m][n][j];
          size_t bh = (size_t)(b * 16 + h);
          if (which == 0) q[(bh * 2048 + t) * 64 + d]  = (bf16)(v * QSCALE);
          else            kk[(bh * 2048 + t) * 64 + d] = (bf16)v;
        }
  }
}

// ---- final GEMM: attn[4096,1024] @ WoutT[1024,1024]^T -> out fp32 ----
__global__ __launch_bounds__(256) void gemm_out(const bf16* __restrict__ A,
                                                const bf16* __restrict__ Bt,
                                                float* __restrict__ C) {
  __shared__ bf16 As[2][128 * 32];
  __shared__ bf16 Bs[2][128 * 32];
  int id = blockIdx.x;
  int bn = id & 7, bm = id >> 3;
  int m0 = bm * 128, n0 = bn * 128;
  f32x4 acc[4][4];
  gemm_mainloop_db(A, Bt, 1024, m0, n0, acc, As[0], Bs[0]);
  int lane = threadIdx.x & 63;
  int wave = threadIdx.x >> 6;
  int wr = wave >> 1, wc = wave & 1;
#pragma unroll
  for (int m = 0; m < 4; m++)
#pragma unroll
    for (int n = 0; n < 4; n++)
#pragma unroll
      for (int j = 0; j < 4; j++) {
        int gm = m0 + wr * 64 + m * 16 + (lane >> 4) * 4 + j;
        int gn = n0 + wc * 64 + n * 16 + (lane & 15);
        C[(size_t)gm * 1024 + gn] = acc[m][n][j];
      }
}

// ---------------- flash attention v8 (uniform paired blocks) ----------------
// 512 blocks x 256 threads (4 waves). Each block runs TWO q-tiles (qx, 31-qx)
// sequentially -> every block does exactly 33 tile-steps: zero tail imbalance.
// Per-phase math identical to v7 (swapped QK^T, exp2 softmax, defer-max,
// 2-buf K/V prefetch-before-compute, hoisted swizzled offsets).
__global__ __launch_bounds__(256) void attn(const bf16* __restrict__ q,
                                            const bf16* __restrict__ kk,
                                            const bf16* __restrict__ vt,
                                            bf16* __restrict__ out) {
  __shared__ bf16 Ks[2][64 * 64];   // 16 KB (chunk-XOR swizzled)
  __shared__ bf16 Vs[2][64 * 64];   // 16 KB (chunk-XOR swizzled)
  __shared__ bf16 PQ[64 * 64];      // 8 KB: Q staging (per phase) / P tiles
  int tid = threadIdx.x, lane = tid & 63, w = tid >> 6;
  int c16 = lane & 15, g = (lane >> 4) & 3, g4 = g * 4;

  // ---- decode: 512 = 8 XCD x (4 bh x 16 pairs) ----
  int id = blockIdx.x;
  int c = id & 7;
  int k = id >> 3;          // 0..63
  int bhi = k & 3;
  int pq = k >> 2;          // 0..15
  int bh = 4 * c + bhi;     // 4 bh per XCD (K/V L2-resident)

  const bf16* qb = q  + (size_t)bh * 2048 * 64;
  const bf16* kb = kk + (size_t)bh * 2048 * 64;
  const bf16* vb = vt + (size_t)bh * 64 * 2048;
  int b = bh >> 4, h = bh & 15;

  // ---- hoisted swizzled LDS byte offsets (lane-only, phase-invariant) ----
  int koff[2][4];
#pragma unroll
  for (int ks = 0; ks < 2; ks++)
#pragma unroll
    for (int n = 0; n < 4; n++) {
      int srow = n * 16 + c16;
      koff[ks][n] = srow * 128 + (((ks * 4 + g) ^ (srow & 7)) << 4);
    }
  int pwoff[4];
#pragma unroll
  for (int n = 0; n < 4; n++)
    pwoff[n] = (c16 * 64 + (((2 * n + (g >> 1)) ^ (c16 & 7)) * 8) + (g & 1) * 4) * 2;
  int proff[2];
#pragma unroll
  for (int ks = 0; ks < 2; ks++)
    proff[ks] = (c16 * 64 + (((ks * 4 + g) ^ (c16 & 7)) * 8)) * 2;
  char* Pb = (char*)PQ + w * 2048;   // 16x64 per-wave P tile

  for (int half = 0; half < 2; ++half) {
    int qx = half ? (31 - pq) : pq;
    int q0 = qx * 64;
    int nt = qx + 1;
    if (half) __syncthreads();   // prior phase's LDS reads fully done

    // ---- phase prologue: stage Q[64][64] + K/V tile 0 ----
#pragma unroll
    for (int i = 0; i < 2; i++) {
      int cc = tid + i * 256;            // 0..511
      int r = cc >> 3, ds = (cc & 7) * 8;
      GLOAD16(qb + (size_t)(q0 + r) * 64 + ds, PQ + cc * 8);
    }
#pragma unroll
    for (int i = 0; i < 2; i++) {
      int cc = tid + i * 256;
      int r = cc >> 3, p = cc & 7;
      GLOAD16(kb + (size_t)r * 64 + ((p ^ (r & 7)) * 8), Ks[0] + cc * 8);
      GLOAD16(vb + (size_t)r * 2048 + ((p ^ (r & 7)) * 8), Vs[0] + cc * 8);
    }
    __syncthreads();
    bf16x8 qf[2];
#pragma unroll
    for (int ks = 0; ks < 2; ks++)
      qf[ks] = *(const bf16x8*)(PQ + (w * 16 + c16) * 64 + ks * 32 + g * 8);
    __syncthreads();   // all waves done reading Q (PQ becomes P storage)

    f32x4 o[4];
    float mrun = -__builtin_inff(), lrun = 0.f;
    {
      f32x4 z = {0.f, 0.f, 0.f, 0.f};
#pragma unroll
      for (int n = 0; n < 4; n++) o[n] = z;
    }
    int qlo = q0 + w * 16;
    int qr = qlo + c16;

    for (int t = 0; t < nt; ++t) {
      int s0 = t * 64;
      int cb = t & 1;
      if (t + 1 < nt) {              // prefetch t+1 (issued before compute)
        int sn = s0 + 64;
#pragma unroll
        for (int i = 0; i < 2; i++) {
          int cc = tid + i * 256;
          int r = cc >> 3, p = cc & 7;
          GLOAD16(kb + (size_t)(sn + r) * 64 + ((p ^ (r & 7)) * 8), Ks[cb ^ 1] + cc * 8);
          GLOAD16(vb + (size_t)r * 2048 + sn + ((p ^ (r & 7)) * 8), Vs[cb ^ 1] + cc * 8);
        }
      }
      const char* Kb = (const char*)Ks + cb * 8192;
      const char* Vb = (const char*)Vs + cb * 8192;
      if (s0 <= qlo + 15) {   // wave-uniform causal skip
        // ---- QK^T: S^T = mfma(K, Q); lane holds S[q=c16][s=n*16+g4+r] ----
        f32x4 S[4];
        {
          f32x4 z = {0.f, 0.f, 0.f, 0.f};
#pragma unroll
          for (int n = 0; n < 4; n++) S[n] = z;
        }
        __builtin_amdgcn_s_setprio(1);
#pragma unroll
        for (int ks = 0; ks < 2; ks++) {
          bf16x8 kf[4];
#pragma unroll
          for (int n = 0; n < 4; n++)
            kf[n] = *(const bf16x8*)(Kb + koff[ks][n]);
#pragma unroll
          for (int n = 0; n < 4; n++)
            S[n] = MFMA16(kf[n], qf[ks], S[n]);
        }
        __builtin_amdgcn_s_setprio(0);
        // ---- causal mask (diag tiles only) ----
        if (s0 + 63 > qlo) {
#pragma unroll
          for (int n = 0; n < 4; n++)
#pragma unroll
            for (int r = 0; r < 4; r++)
              if (s0 + n * 16 + g4 + r > qr) S[n][r] = -__builtin_inff();
        }
        // ---- online softmax (exp2 domain), defer-max ----
        float tm = fmaxf(fmaxf(fmaxf(S[0][0], S[0][1]), fmaxf(S[0][2], S[0][3])),
                         fmaxf(fmaxf(S[1][0], S[1][1]), fmaxf(S[1][2], S[1][3])));
        tm = fmaxf(tm, fmaxf(fmaxf(fmaxf(S[2][0], S[2][1]), fmaxf(S[2][2], S[2][3])),
                             fmaxf(fmaxf(S[3][0], S[3][1]), fmaxf(S[3][2], S[3][3]))));
        tm = fmaxf(tm, __shfl_xor(tm, 16));
        tm = fmaxf(tm, __shfl_xor(tm, 32));
        if (!__all(tm <= mrun + 8.f)) {   // rescale (rare after first tile)
          float mnew = fmaxf(mrun, tm);
          float corr = EXP2F(mrun - mnew);
          lrun *= corr;
          mrun = mnew;
#pragma unroll
          for (int j = 0; j < 4; j++) {
            float cj = __shfl(corr, (lane & 48) | (g4 + j));
#pragma unroll
            for (int n = 0; n < 4; n++) o[n][j] *= cj;
          }
        }
        float p[4][4];
        float rs = 0.f;
#pragma unroll
        for (int n = 0; n < 4; n++)
#pragma unroll
          for (int r = 0; r < 4; r++) {
            p[n][r] = EXP2F(S[n][r] - mrun);
            rs += p[n][r];
          }
        rs += __shfl_xor(rs, 16);
        rs += __shfl_xor(rs, 32);
        lrun += rs;
        // ---- pack P to LDS ----
#pragma unroll
        for (int n = 0; n < 4; n++) {
          bf16x4 pw;
          pw[0] = (bf16)p[n][0]; pw[1] = (bf16)p[n][1];
          pw[2] = (bf16)p[n][2]; pw[3] = (bf16)p[n][3];
          *(bf16x4*)(Pb + pwoff[n]) = pw;
        }
        // ---- PV: o[q][d] += P[q][s] V^T[d][s]^T ----
        __builtin_amdgcn_s_setprio(1);
#pragma unroll
        for (int ks = 0; ks < 2; ks++) {
          bf16x8 vf[4];
#pragma unroll
          for (int n = 0; n < 4; n++)
            vf[n] = *(const bf16x8*)(Vb + koff[ks][n]);
          bf16x8 pf = *(const bf16x8*)(Pb + proff[ks]);
#pragma unroll
          for (int n = 0; n < 4; n++)
            o[n] = MFMA16(pf, vf[n], o[n]);
        }
        __builtin_amdgcn_s_setprio(0);
      }
      if (t + 1 < nt) {
        asm volatile("s_waitcnt vmcnt(0)" ::: "memory");  // t+1 staged
        __builtin_amdgcn_s_barrier();
        __builtin_amdgcn_sched_barrier(0);
      }
    }
    // ---- phase epilogue: o row q = qlo+g4+j, col d = n*16+c16 ----
#pragma unroll
    for (int j = 0; j < 4; j++) {
      float lv = __shfl(lrun, (lane & 48) | (g4 + j));
      float inv = 1.f / lv;
      int t = qlo + g4 + j;
#pragma unroll
      for (int n = 0; n < 4; n++) {
        int col = h * 64 + n * 16 + c16;
        out[((size_t)(b * 2048 + t)) * 1024 + col] = (bf16)(o[n][j] * inv);
      }
    }
  }
}

extern "C" void kernel_launch(void* const* d_in, const int* in_sizes, int n_in,
                              void* d_out, int out_size, void* d_ws, size_t ws_size,
                              hipStream_t stream) {
  const float* x    = (const float*)d_in[0];
  const float* Wqkv = (const float*)d_in[1];
  const float* Wout = (const float*)d_in[2];
  float* outp = (float*)d_out;
  char* ws = (char*)d_ws;
  const size_t MB = 1024 * 1024;
  bf16* xb    = (bf16*)(ws);             // 8 MB [4096][1024]; later reused as attn out
  bf16* wqkvT = (bf16*)(ws + 8 * MB);    // 6 MB [3072][1024]
  bf16* woutT = (bf16*)(ws + 14 * MB);   // 2 MB [1024][1024]
  bf16* qb    = (bf16*)(ws + 16 * MB);   // 8 MB [32][2048][64] (scaled 0.125*log2e)
  bf16* kb    = (bf16*)(ws + 24 * MB);   // 8 MB [32][2048][64]
  bf16* vtb   = (bf16*)(ws + 32 * MB);   // 8 MB [32][64][2048]

  hipLaunchKernelGGL(prep, dim3(6144), dim3(256), 0, stream,
                     x, Wqkv, Wout, xb, wqkvT, woutT);
  hipLaunchKernelGGL(gemm_qkv, dim3(768), dim3(256), 0, stream,
                     xb, wqkvT, qb, kb, vtb);
  hipLaunchKernelGGL(attn, dim3(512), dim3(256), 0, stream,
                     qb, kb, vtb, xb);
  hipLaunchKernelGGL(gemm_out, dim3(256), dim3(256), 0, stream,
                     xb, woutT, outp);
}